// Round 1
// baseline (83.989 us; speedup 1.0000x reference)
//
#include <hip/hip_runtime.h>
#include <stdint.h>

#define D 128
#define CLASS_NUM 7
#define QS 150
#define QROWS 1050       // CLASS_NUM*QS
#define MB 128           // B-rows per block
#define NQT 9            // ceil(QROWS/128)
#define THREADS 512
#define C_2LOG2E 2.8853900817779268f   // 2/ln(2): exp(2s) = exp2(s*C)

typedef float f32x4 __attribute__((ext_vector_type(4)));
typedef short bf16x8 __attribute__((ext_vector_type(8)));

// round-to-nearest-even fp32 -> bf16, packed pair (lo = first elem)
__device__ __forceinline__ unsigned f2bf_pack(float a, float b) {
  union { float f; unsigned u; } x, y;
  x.f = a; y.f = b;
  unsigned ua = x.u + 0x7fffu + ((x.u >> 16) & 1u);
  unsigned ub = y.u + 0x7fffu + ((y.u >> 16) & 1u);
  return (ua >> 16) | (ub & 0xffff0000u);
}

// XOR-swizzled LDS byte offset for a row-major [row][128] bf16 tile (256 B/row)
__device__ __forceinline__ int swz(int row, int byte_in_row) {
  return (row << 8) + (byte_in_row ^ ((row & 7) << 4));
}

__global__ __launch_bounds__(THREADS) void pgc_kernel(
    const float* __restrict__ act, const float* __restrict__ ema,
    const float* __restrict__ plab, const float* __restrict__ queue,
    float* __restrict__ out)
{
  __shared__ __align__(16) char sbuf[MB * 256];   // 32 KB bf16 tile (A, then queue tiles)
  __shared__ float s_lpos[MB];
  __shared__ int   s_lab[MB];
  __shared__ float s_wsum[8];

  const int tid  = threadIdx.x;
  const int lane = tid & 63;
  const int wave = tid >> 6;
  const int lo = lane & 15, hi = lane >> 4;

  // ---------------- prologue: per-row norms, lpos dot, label, stage A as bf16
  {
    const int r = tid >> 2;          // local row 0..127
    const int s = tid & 3;           // quarter of the row
    const long grow = (long)blockIdx.x * MB + r;
    const float* ap = act + grow * D + s * 32;
    const float* ep = ema + grow * D + s * 32;
    float a[32];
    float a2 = 0.f, e2 = 0.f, ae = 0.f;
#pragma unroll
    for (int j = 0; j < 8; ++j) {
      const float4 av = *(const float4*)(ap + 4 * j);
      const float4 ev = *(const float4*)(ep + 4 * j);
      a[4*j+0] = av.x; a[4*j+1] = av.y; a[4*j+2] = av.z; a[4*j+3] = av.w;
      a2 += av.x*av.x + av.y*av.y + av.z*av.z + av.w*av.w;
      e2 += ev.x*ev.x + ev.y*ev.y + ev.z*ev.z + ev.w*ev.w;
      ae += av.x*ev.x + av.y*ev.y + av.z*ev.z + av.w*ev.w;
    }
#pragma unroll
    for (int m = 1; m < 4; m <<= 1) {
      a2 += __shfl_xor(a2, m);
      e2 += __shfl_xor(e2, m);
      ae += __shfl_xor(ae, m);
    }
    const float rna = rsqrtf(a2);
    const float rne = rsqrtf(e2);
    if (s == 0) s_lpos[r] = ae * rna * rne;
    if (s == 1) {
      const float* pp = plab + grow * CLASS_NUM;
      float best = pp[0]; int bi = 0;
#pragma unroll
      for (int c = 1; c < CLASS_NUM; ++c) {
        float v = pp[c];
        if (v > best) { best = v; bi = c; }
      }
      s_lab[r] = bi;
    }
    // stage normalized row as bf16 (swizzled)
#pragma unroll
    for (int j = 0; j < 16; ++j) {
      *(unsigned*)(sbuf + swz(r, s * 64 + 4 * j)) =
          f2bf_pack(a[2*j] * rna, a[2*j+1] * rna);
    }
  }
  __syncthreads();

  // ---------------- load A fragments (held in regs for the whole sweep) + labels
  bf16x8 afrag[4];
  const int arow = wave * 16 + lo;
#pragma unroll
  for (int k = 0; k < 4; ++k)
    afrag[k] = *(const bf16x8*)(sbuf + swz(arow, k * 64 + hi * 16));
  int lab[4];
#pragma unroll
  for (int rg = 0; rg < 4; ++rg) lab[rg] = s_lab[wave * 16 + hi * 4 + rg];
  __syncthreads();   // sbuf about to be reused for queue tiles

  float denom[4] = {0.f, 0.f, 0.f, 0.f};
  float pdot[4]  = {0.f, 0.f, 0.f, 0.f};

  // ---------------- queue sweep: 9 tiles of 128 queue rows
  for (int t = 0; t < NQT; ++t) {
    const int qbase = t * 128;
    // stage queue tile fp32 -> bf16 (swizzled); pad rows >= QROWS with zeros
#pragma unroll
    for (int i = 0; i < 16; ++i) {
      const int idx = tid + i * THREADS;
      const int row = idx >> 6, kp = idx & 63;
      const int q = qbase + row;
      unsigned pk = 0u;
      if (q < QROWS) {
        const float2 v = *(const float2*)(queue + (long)q * D + kp * 2);
        pk = f2bf_pack(v.x, v.y);
      }
      *(unsigned*)(sbuf + swz(row, kp * 4)) = pk;
    }
    __syncthreads();

#pragma unroll
    for (int n = 0; n < 8; ++n) {
      f32x4 acc = {0.f, 0.f, 0.f, 0.f};
#pragma unroll
      for (int k = 0; k < 4; ++k) {
        const bf16x8 bfrag =
            *(const bf16x8*)(sbuf + swz(n * 16 + lo, k * 64 + hi * 16));
        acc = __builtin_amdgcn_mfma_f32_16x16x32_bf16(afrag[k], bfrag, acc, 0, 0, 0);
      }
      const int q = qbase + n * 16 + lo;       // this lane's queue row (D-col)
      const int qc = (q * 6991) >> 20;         // q / 150 (exact for q < 1056)
      const bool valid = q < QROWS;
#pragma unroll
      for (int rg = 0; rg < 4; ++rg) {
        const float sv = acc[rg];
        const float e = exp2f(sv * C_2LOG2E);  // exp(2*s)
        denom[rg] += valid ? e : 0.0f;
        pdot[rg]  += (valid && (qc == lab[rg])) ? sv : 0.0f;
      }
    }
    __syncthreads();
  }

  // ---------------- reduce across the 16 q-column lanes of each row
#pragma unroll
  for (int rg = 0; rg < 4; ++rg) {
#pragma unroll
    for (int m = 1; m < 16; m <<= 1) {
      denom[rg] += __shfl_xor(denom[rg], m);
      pdot[rg]  += __shfl_xor(pdot[rg], m);
    }
  }

  float loss = 0.f;
  if (lo == 0) {
#pragma unroll
    for (int rg = 0; rg < 4; ++rg) {
      const int r = wave * 16 + hi * 4 + rg;
      const float lp = exp2f(s_lpos[r] * C_2LOG2E);   // exp(2*<f,ema_f>)
      const float dn = lp + denom[rg];
      // term0 (exact, incl. eps) + 150*log(dn) - 2*sum(s_q) ; log1p(eps..) dropped (<1e-5)
      loss += -logf(lp / dn + 1e-8f) + 150.0f * logf(dn) - 2.0f * pdot[rg];
    }
  }
#pragma unroll
  for (int m = 1; m < 64; m <<= 1) loss += __shfl_xor(loss, m);
  if (lane == 0) s_wsum[wave] = loss;
  __syncthreads();
  if (tid == 0) {
    float tot = 0.f;
#pragma unroll
    for (int w = 0; w < 8; ++w) tot += s_wsum[w];
    atomicAdd(out, tot * (1.0f / (151.0f * 65536.0f)));
  }
}

extern "C" void kernel_launch(void* const* d_in, const int* in_sizes, int n_in,
                              void* d_out, int out_size, void* d_ws, size_t ws_size,
                              hipStream_t stream) {
  const float* act   = (const float*)d_in[0];
  const float* ema   = (const float*)d_in[1];
  const float* plab  = (const float*)d_in[2];
  const float* queue = (const float*)d_in[3];
  float* out = (float*)d_out;

  hipMemsetAsync(d_out, 0, sizeof(float), stream);  // replays don't re-zero d_out
  const int nblocks = 65536 / MB;                   // 512
  pgc_kernel<<<dim3(nblocks), dim3(THREADS), 0, stream>>>(act, ema, plab, queue, out);
}

// Round 5
// 70.773 us; speedup vs baseline: 1.1867x; 1.1867x over previous
//
#include <hip/hip_runtime.h>
#include <stdint.h>

#define CLASS_NUM 7
#define QROWS 1050
#define QPAD  1152            // 18 tiles * 64 rows; pad rows are zero
#define NPAD  102             // QPAD - QROWS (each pad row adds exp2(0)=1 to dn)
#define MBR   128             // B-rows per block
#define NTHREADS 256          // 4 waves; each wave owns 32 B-rows
#define NQT   18
#define TBYTES 16384          // 64 rows * 256 B (bf16)
#define QSUM_OFF (QPAD * 256) // byte offset of the 7x128 fp32 class sums in d_ws
#define C2L 2.8853900817779268f   // 2/ln2 : exp(2s) = exp2(s*C2L)

typedef float f32x4 __attribute__((ext_vector_type(4)));
typedef short bf16x8 __attribute__((ext_vector_type(8)));

// round-to-nearest-even fp32 -> bf16 pair packed in a dword (lo = first)
__device__ __forceinline__ unsigned f2bf_pack(float a, float b) {
  union { float f; unsigned u; } x, y;
  x.f = a; y.f = b;
  unsigned ua = x.u + 0x7fffu + ((x.u >> 16) & 1u);
  unsigned ub = y.u + 0x7fffu + ((y.u >> 16) & 1u);
  return (ua >> 16) | (ub & 0xffff0000u);
}

// XOR-swizzled LDS byte offset within a row-major [row][128] bf16 tile (256 B/row)
__device__ __forceinline__ int swz(int row, int byte_in_row) {
  return (row << 8) + (byte_in_row ^ ((row & 7) << 4));
}

// ---- prep A: queue fp32 -> bf16, zero-padded to QPAD rows, PRE-swizzled so a
// linear global_load_lds copy lands swizzle-correct in LDS (rule #21).
__global__ void prep_queue(const float* __restrict__ queue, unsigned* __restrict__ wsq) {
  const int i = blockIdx.x * 256 + threadIdx.x;   // dword index, QPAD*64 total
  if (i >= QPAD * 64) return;
  const int row = i >> 6;
  const int pb  = (i & 63) << 2;                  // physical byte-in-row
  const int lb  = pb ^ ((row & 7) << 4);          // logical byte-in-row
  unsigned pk = 0u;
  if (row < QROWS) {
    const float2 v = *(const float2*)(queue + row * 128 + (lb >> 1));
    pk = f2bf_pack(v.x, v.y);
  }
  wsq[i] = pk;
}

// ---- prep B: per-class queue-row sums, qsum[c][d] = sum_{i<150} queue[c*150+i][d]
__global__ void prep_qsum(const float* __restrict__ queue, float* __restrict__ qsum) {
  const int c = blockIdx.x, d = threadIdx.x;      // 7 blocks x 128 threads
  float s = 0.f;
  const float* p = queue + c * 150 * 128 + d;
  for (int i = 0; i < 150; ++i) s += p[i * 128];
  qsum[c * 128 + d] = s;
}

__global__ __launch_bounds__(NTHREADS, 2) void pgc_main(
    const float* __restrict__ act, const float* __restrict__ ema,
    const float* __restrict__ plab, const char* __restrict__ ws,
    float* __restrict__ out)
{
  __shared__ __align__(16) char aT[MBR * 256];    // 32 KB A tile (bf16, swizzled)
  __shared__ __align__(16) char qT[2][TBYTES];    // 2 x 16 KB queue tile dbuf

  const int tid  = threadIdx.x;
  const int lane = tid & 63;
  const int wave = tid >> 6;
  const int lo = lane & 15, hi = lane >> 4;

  // ---- issue tile-0 staging DMA first (hides under the prologue)
  {
    const char* gs = ws + wave * 4096 + lane * 16;
    char* ld = qT[0] + wave * 4096;
#pragma unroll
    for (int ii = 0; ii < 4; ++ii)
      __builtin_amdgcn_global_load_lds(
          (const __attribute__((address_space(1))) void*)(gs + ii * 1024),
          (__attribute__((address_space(3))) void*)(ld + ii * 1024), 16, 0, 0);
  }

  // ---- prologue: 2 threads/row; norms, lpos, label, pos-dot, stage A (x C2L)
  float mylpos, mypd;
  {
    const int r = tid >> 1, h = tid & 1;
    const long grow = (long)blockIdx.x * MBR + r;
    const float* ap = act + grow * 128 + h * 64;
    const float* ep = ema + grow * 128 + h * 64;
    float4 a4[16];
    float a2 = 0.f, e2 = 0.f, ae = 0.f;
#pragma unroll
    for (int j = 0; j < 16; ++j) {
      a4[j] = *(const float4*)(ap + 4 * j);
      const float4 ev = *(const float4*)(ep + 4 * j);
      a2 += a4[j].x * a4[j].x + a4[j].y * a4[j].y + a4[j].z * a4[j].z + a4[j].w * a4[j].w;
      e2 += ev.x * ev.x + ev.y * ev.y + ev.z * ev.z + ev.w * ev.w;
      ae += a4[j].x * ev.x + a4[j].y * ev.y + a4[j].z * ev.z + a4[j].w * ev.w;
    }
    a2 += __shfl_xor(a2, 1);
    e2 += __shfl_xor(e2, 1);
    ae += __shfl_xor(ae, 1);
    const float rna = rsqrtf(a2), rne = rsqrtf(e2);
    mylpos = ae * rna * rne * C2L;

    int mylab;
    {
      const float* pp = plab + grow * CLASS_NUM;
      float best = pp[0]; int bi = 0;
#pragma unroll
      for (int c = 1; c < CLASS_NUM; ++c) {
        const float v = pp[c];
        if (v > best) { best = v; bi = c; }
      }
      mylab = bi;
    }

    // positive-sum via precomputed class sums: <f, qsum[lab]> (fp32-exact path)
    {
      const float* qs = (const float*)(ws + QSUM_OFF) + mylab * 128 + h * 64;
      float pdot = 0.f;
#pragma unroll
      for (int j = 0; j < 16; ++j) {
        const float4 qv = *(const float4*)(qs + 4 * j);
        pdot += a4[j].x * qv.x + a4[j].y * qv.y + a4[j].z * qv.z + a4[j].w * qv.w;
      }
      pdot *= rna;
      mypd = pdot + __shfl_xor(pdot, 1);   // full-row positive dot sum
    }

    const float sc = rna * C2L;   // pre-scale A so MFMA output is 2s/ln2
#pragma unroll
    for (int j = 0; j < 32; ++j) {
      const float e0 = ((const float*)&a4[j >> 1])[(j & 1) * 2];
      const float e1 = ((const float*)&a4[j >> 1])[(j & 1) * 2 + 1];
      *(unsigned*)(aT + swz(r, h * 128 + 4 * j)) = f2bf_pack(e0 * sc, e1 * sc);
    }
  }
  __syncthreads();   // A tile staged + tile-0 DMA drained (barrier waits vmcnt)

  // ---- per-wave A fragments: 2 sets of 16 rows, held for the whole sweep
  bf16x8 af[2][4];
#pragma unroll
  for (int s = 0; s < 2; ++s)
#pragma unroll
    for (int k = 0; k < 4; ++k)
      af[s][k] = *(const bf16x8*)(aT + swz(wave * 32 + s * 16 + lo, k * 64 + hi * 16));

  float dn[2][4] = {{0.f,0.f,0.f,0.f},{0.f,0.f,0.f,0.f}};

  // ---- queue sweep: 18 tiles of 64 rows, double-buffered DMA staging
  for (int t = 0; t < NQT; ++t) {
    const int cur = t & 1;
    if (t < NQT - 1) {
      const char* gs = ws + (size_t)(t + 1) * TBYTES + wave * 4096 + lane * 16;
      char* ld = qT[cur ^ 1] + wave * 4096;
#pragma unroll
      for (int ii = 0; ii < 4; ++ii)
        __builtin_amdgcn_global_load_lds(
            (const __attribute__((address_space(1))) void*)(gs + ii * 1024),
            (__attribute__((address_space(3))) void*)(ld + ii * 1024), 16, 0, 0);
    }
    const char* qb = qT[cur];
#pragma unroll
    for (int n = 0; n < 4; ++n) {
      bf16x8 bf[4];
#pragma unroll
      for (int k = 0; k < 4; ++k)
        bf[k] = *(const bf16x8*)(qb + swz(n * 16 + lo, k * 64 + hi * 16));
      f32x4 acc0 = {0.f, 0.f, 0.f, 0.f}, acc1 = {0.f, 0.f, 0.f, 0.f};
#pragma unroll
      for (int k = 0; k < 4; ++k)
        acc0 = __builtin_amdgcn_mfma_f32_16x16x32_bf16(af[0][k], bf[k], acc0, 0, 0, 0);
#pragma unroll
      for (int k = 0; k < 4; ++k)
        acc1 = __builtin_amdgcn_mfma_f32_16x16x32_bf16(af[1][k], bf[k], acc1, 0, 0, 0);
#pragma unroll
      for (int rg = 0; rg < 4; ++rg) {
        dn[0][rg] += exp2f(acc0[rg]);   // pad rows contribute 1.0; removed later
        dn[1][rg] += exp2f(acc1[rg]);
      }
    }
    __syncthreads();   // all reads of cur done + prefetch drained (next ready)
  }

  // ---- reduce across the 16 q-column lanes of each row
#pragma unroll
  for (int s = 0; s < 2; ++s)
#pragma unroll
    for (int rg = 0; rg < 4; ++rg)
#pragma unroll
      for (int m = 1; m < 16; m <<= 1)
        dn[s][rg] += __shfl_xor(dn[s][rg], m);

  float loss = 0.f;
  if (lo == 0) {
#pragma unroll
    for (int s = 0; s < 2; ++s)
#pragma unroll
      for (int rg = 0; rg < 4; ++rg) {
        const int idx = (s * 16 + hi * 4 + rg) * 2;   // lane holding this row
        const float lp  = exp2f(__shfl(mylpos, idx)); // exp(2*<f,ema_f>)
        const float pdr = __shfl(mypd, idx);          // fp32 positive dot sum
        const float dnf = lp + dn[s][rg] - (float)NPAD;
        loss += -logf(lp / dnf + 1e-8f) + 150.0f * logf(dnf) - 2.0f * pdr;
      }
  }
#pragma unroll
  for (int m = 1; m < 64; m <<= 1) loss += __shfl_xor(loss, m);

  float* swsum = (float*)aT;   // aT dead past afrag loads; reuse for block sum
  if (lane == 0) swsum[wave] = loss;
  __syncthreads();
  if (tid == 0)
    atomicAdd(out, (swsum[0] + swsum[1] + swsum[2] + swsum[3]) *
                       (1.0f / (151.0f * 65536.0f)));
}

extern "C" void kernel_launch(void* const* d_in, const int* in_sizes, int n_in,
                              void* d_out, int out_size, void* d_ws, size_t ws_size,
                              hipStream_t stream) {
  const float* act   = (const float*)d_in[0];
  const float* ema   = (const float*)d_in[1];
  const float* plab  = (const float*)d_in[2];
  const float* queue = (const float*)d_in[3];
  float* out = (float*)d_out;

  hipMemsetAsync(d_out, 0, sizeof(float), stream);

  prep_queue<<<dim3((QPAD * 64 + 255) / 256), dim3(256), 0, stream>>>(
      queue, (unsigned*)d_ws);
  prep_qsum<<<dim3(CLASS_NUM), dim3(128), 0, stream>>>(
      queue, (float*)((char*)d_ws + QSUM_OFF));

  pgc_main<<<dim3(65536 / MBR), dim3(NTHREADS), 0, stream>>>(
      act, ema, plab, (const char*)d_ws, out);
}

// Round 6
// 64.993 us; speedup vs baseline: 1.2923x; 1.0889x over previous
//
#include <hip/hip_runtime.h>
#include <stdint.h>

#define CLASS_NUM 7
#define QROWS 1050
#define QPAD  1152            // 18 tiles * 64 rows; pad rows are zero
#define NPAD  102             // each pad row adds exp2(0)=1 to dn
#define NQT   18
#define TBYTES 16384          // 64 rows * 256 B (bf16)
#define QSUM_OFF (QPAD * 256)             // 294912: 7x128 fp32 class sums
#define A_OFF    (1 << 19)                // 524288: frag-ordered bf16 A (16 MB)
#define LPOS_OFF (A_OFF + (1 << 24))      // float[65536]
#define PD_OFF   (LPOS_OFF + (1 << 18))   // float[65536]
#define WS_NEED  ((size_t)PD_OFF + (1 << 18))
#define C2L 2.8853900817779268f           // 2/ln2 : exp(2s) = exp2(s*C2L)

typedef float f32x4 __attribute__((ext_vector_type(4)));
typedef short bf16x8 __attribute__((ext_vector_type(8)));

__device__ __forceinline__ unsigned f2bf_pack(float a, float b) {
  union { float f; unsigned u; } x, y;
  x.f = a; y.f = b;
  unsigned ua = x.u + 0x7fffu + ((x.u >> 16) & 1u);
  unsigned ub = y.u + 0x7fffu + ((y.u >> 16) & 1u);
  return (ua >> 16) | (ub & 0xffff0000u);
}

// XOR-swizzled byte offset within a row-major [row][128] bf16 tile (256 B/row)
__device__ __forceinline__ int swz(int row, int byte_in_row) {
  return (row << 8) + (byte_in_row ^ ((row & 7) << 4));
}

// ---- prep A: queue fp32 -> bf16, zero-padded, PRE-swizzled for linear DMA
__global__ void prep_queue(const float* __restrict__ queue, unsigned* __restrict__ wsq) {
  const int i = blockIdx.x * 256 + threadIdx.x;
  if (i >= QPAD * 64) return;
  const int row = i >> 6;
  const int pb  = (i & 63) << 2;
  const int lb  = pb ^ ((row & 7) << 4);
  unsigned pk = 0u;
  if (row < QROWS) {
    const float2 v = *(const float2*)(queue + row * 128 + (lb >> 1));
    pk = f2bf_pack(v.x, v.y);
  }
  wsq[i] = pk;
}

// ---- prep B: per-class queue-row sums
__global__ void prep_qsum(const float* __restrict__ queue, float* __restrict__ qsum) {
  const int c = blockIdx.x, d = threadIdx.x;
  float s = 0.f;
  const float* p = queue + c * 150 * 128 + d;
  for (int i = 0; i < 150; ++i) s += p[i * 128];
  qsum[c * 128 + d] = s;
}

// ---- prep C: per-row stats + frag-ordered prescaled bf16 A.
// 8 threads/row, 32 rows/block, 2048 blocks. Memory-bound, high occupancy.
__global__ __launch_bounds__(256) void prep_act(
    const float* __restrict__ act, const float* __restrict__ ema,
    const float* __restrict__ plab, char* __restrict__ ws)
{
  const int tid = threadIdx.x;
  const int j8 = tid & 7;                       // chunk within row (16 floats)
  const long r = (long)blockIdx.x * 32 + (tid >> 3);
  const float* ap = act + r * 128 + j8 * 16;
  const float* ep = ema + r * 128 + j8 * 16;
  float4 a[4];
  float a2 = 0.f, e2 = 0.f, ae = 0.f;
#pragma unroll
  for (int u = 0; u < 4; ++u) {
    a[u] = *(const float4*)(ap + 4 * u);
    const float4 ev = *(const float4*)(ep + 4 * u);
    a2 += a[u].x * a[u].x + a[u].y * a[u].y + a[u].z * a[u].z + a[u].w * a[u].w;
    e2 += ev.x * ev.x + ev.y * ev.y + ev.z * ev.z + ev.w * ev.w;
    ae += a[u].x * ev.x + a[u].y * ev.y + a[u].z * ev.z + a[u].w * ev.w;
  }
#pragma unroll
  for (int m = 1; m < 8; m <<= 1) {
    a2 += __shfl_xor(a2, m);
    e2 += __shfl_xor(e2, m);
    ae += __shfl_xor(ae, m);
  }
  const float rna = rsqrtf(a2), rne = rsqrtf(e2);

  // argmax over 7 classes via 8-lane vote (first-max tie rule)
  float v = (j8 < CLASS_NUM) ? plab[r * CLASS_NUM + j8] : -3.4e38f;
  int bi = j8;
#pragma unroll
  for (int m = 1; m < 8; m <<= 1) {
    const float ov = __shfl_xor(v, m);
    const int   oi = __shfl_xor(bi, m);
    if (ov > v || (ov == v && oi < bi)) { v = ov; bi = oi; }
  }

  // positive-sum via class sums (fp32-exact)
  const float* qs = (const float*)(ws + QSUM_OFF) + bi * 128 + j8 * 16;
  float pdot = 0.f;
#pragma unroll
  for (int u = 0; u < 4; ++u) {
    const float4 qv = *(const float4*)(qs + 4 * u);
    pdot += a[u].x * qv.x + a[u].y * qv.y + a[u].z * qv.z + a[u].w * qv.w;
  }
#pragma unroll
  for (int m = 1; m < 8; m <<= 1) pdot += __shfl_xor(pdot, m);

  if (j8 == 0) {
    ((float*)(ws + LPOS_OFF))[r] = ae * rna * rne * C2L;
    ((float*)(ws + PD_OFF))[r]   = pdot * rna;
  }

  // A write, fragment order: A[G*16+lo][k*32+hi*8..+8] at G*4096+(k*64+hi*16+lo)*16
  const float sc = rna * C2L;
  const int G = (int)(r >> 4), lo = (int)(r & 15);
  const int k = j8 >> 1, hi0 = (j8 & 1) * 2;
#pragma unroll
  for (int u = 0; u < 2; ++u) {
    const float4 p0 = a[u * 2], p1 = a[u * 2 + 1];
    uint4 pk;
    pk.x = f2bf_pack(p0.x * sc, p0.y * sc);
    pk.y = f2bf_pack(p0.z * sc, p0.w * sc);
    pk.z = f2bf_pack(p1.x * sc, p1.y * sc);
    pk.w = f2bf_pack(p1.z * sc, p1.w * sc);
    *(uint4*)(ws + A_OFF + (size_t)G * 4096 +
              (size_t)((k * 64 + (hi0 + u) * 16 + lo) * 16)) = pk;
  }
}

// ---- main GEMM: 512 threads, 8 waves; waves 0-3 sweep q-tiles 0-8,
// waves 4-7 sweep 9-17 (q-split doubles waves/SIMD at same rows/wave).
__global__ __launch_bounds__(512, 2) void pgc_gemm(
    const char* __restrict__ ws, float* __restrict__ out)
{
  __shared__ __align__(16) char qT[2][2][TBYTES];  // [group][dbuf]
  __shared__ float dnsh[8][32];

  const int tid  = threadIdx.x;
  const int lane = tid & 63;
  const int wave = tid >> 6;
  const int grp  = wave >> 2, w4 = wave & 3;
  const int lo = lane & 15, hi = lane >> 4;
  const int T0 = grp * 9;

  // issue first tile staging (hides under A-frag loads)
  {
    const char* gs = ws + (size_t)T0 * TBYTES + w4 * 4096 + lane * 16;
    char* ld = qT[grp][0] + w4 * 4096;
#pragma unroll
    for (int ii = 0; ii < 4; ++ii)
      __builtin_amdgcn_global_load_lds(
          (const __attribute__((address_space(1))) void*)(gs + ii * 1024),
          (__attribute__((address_space(3))) void*)(ld + ii * 1024), 16, 0, 0);
  }

  // A fragments: coalesced dwordx4 from frag-ordered global
  const char* Abase = ws + A_OFF + (size_t)(blockIdx.x * 8 + w4 * 2) * 4096;
  bf16x8 af[2][4];
#pragma unroll
  for (int s = 0; s < 2; ++s)
#pragma unroll
    for (int k = 0; k < 4; ++k)
      af[s][k] = *(const bf16x8*)(Abase + s * 4096 + k * 1024 + lane * 16);

  __syncthreads();   // tile-0 DMA + A loads drained

  float dn[2][4] = {{0.f,0.f,0.f,0.f},{0.f,0.f,0.f,0.f}};

  for (int tt = 0; tt < 9; ++tt) {
    const int cur = tt & 1;
    if (tt < 8) {
      const char* gs = ws + (size_t)(T0 + tt + 1) * TBYTES + w4 * 4096 + lane * 16;
      char* ld = qT[grp][cur ^ 1] + w4 * 4096;
#pragma unroll
      for (int ii = 0; ii < 4; ++ii)
        __builtin_amdgcn_global_load_lds(
            (const __attribute__((address_space(1))) void*)(gs + ii * 1024),
            (__attribute__((address_space(3))) void*)(ld + ii * 1024), 16, 0, 0);
    }
    const char* qb = qT[grp][cur];
#pragma unroll
    for (int n = 0; n < 4; ++n) {
      bf16x8 bf[4];
#pragma unroll
      for (int k = 0; k < 4; ++k)
        bf[k] = *(const bf16x8*)(qb + swz(n * 16 + lo, k * 64 + hi * 16));
      f32x4 acc0 = {0.f, 0.f, 0.f, 0.f}, acc1 = {0.f, 0.f, 0.f, 0.f};
#pragma unroll
      for (int k = 0; k < 4; ++k)
        acc0 = __builtin_amdgcn_mfma_f32_16x16x32_bf16(af[0][k], bf[k], acc0, 0, 0, 0);
#pragma unroll
      for (int k = 0; k < 4; ++k)
        acc1 = __builtin_amdgcn_mfma_f32_16x16x32_bf16(af[1][k], bf[k], acc1, 0, 0, 0);
#pragma unroll
      for (int rg = 0; rg < 4; ++rg) {
        dn[0][rg] += exp2f(acc0[rg]);
        dn[1][rg] += exp2f(acc1[rg]);
      }
    }
    __syncthreads();
  }

  // 16-lane (q-column) reduce
#pragma unroll
  for (int s = 0; s < 2; ++s)
#pragma unroll
    for (int rg = 0; rg < 4; ++rg)
#pragma unroll
      for (int m = 1; m < 16; m <<= 1)
        dn[s][rg] += __shfl_xor(dn[s][rg], m);

  if (lo == 0) {
#pragma unroll
    for (int s = 0; s < 2; ++s)
#pragma unroll
      for (int rg = 0; rg < 4; ++rg)
        dnsh[wave][s * 16 + hi * 4 + rg] = dn[s][rg];
  }
  __syncthreads();

  float loss = 0.f;
  if (grp == 0 && lo == 0) {
    const float* lposArr = (const float*)(ws + LPOS_OFF);
    const float* pdArr   = (const float*)(ws + PD_OFF);
#pragma unroll
    for (int s = 0; s < 2; ++s)
#pragma unroll
      for (int rg = 0; rg < 4; ++rg) {
        const int i = s * 16 + hi * 4 + rg;
        const float dtot = dnsh[w4][i] + dnsh[w4 + 4][i];
        const int R = blockIdx.x * 128 + w4 * 32 + i;
        const float lp  = exp2f(lposArr[R]);
        const float pdr = pdArr[R];
        const float dnf = lp + dtot - (float)NPAD;
        loss += -logf(lp / dnf + 1e-8f) + 150.0f * logf(dnf) - 2.0f * pdr;
      }
  }
#pragma unroll
  for (int m = 1; m < 64; m <<= 1) loss += __shfl_xor(loss, m);

  __syncthreads();   // all reads of dnsh done before reuse
  if (grp == 0 && lane == 0) dnsh[0][w4] = loss;
  __syncthreads();
  if (tid == 0)
    atomicAdd(out, (dnsh[0][0] + dnsh[0][1] + dnsh[0][2] + dnsh[0][3]) *
                       (1.0f / (151.0f * 65536.0f)));
}

// ================= fallback (R5 kernel, needs only ~300 KB ws) =================
__global__ __launch_bounds__(256, 2) void pgc_main(
    const float* __restrict__ act, const float* __restrict__ ema,
    const float* __restrict__ plab, const char* __restrict__ ws,
    float* __restrict__ out)
{
  __shared__ __align__(16) char aT[128 * 256];
  __shared__ __align__(16) char qT[2][TBYTES];
  const int tid = threadIdx.x, lane = tid & 63, wave = tid >> 6;
  const int lo = lane & 15, hi = lane >> 4;
  {
    const char* gs = ws + wave * 4096 + lane * 16;
    char* ld = qT[0] + wave * 4096;
#pragma unroll
    for (int ii = 0; ii < 4; ++ii)
      __builtin_amdgcn_global_load_lds(
          (const __attribute__((address_space(1))) void*)(gs + ii * 1024),
          (__attribute__((address_space(3))) void*)(ld + ii * 1024), 16, 0, 0);
  }
  float mylpos, mypd;
  {
    const int r = tid >> 1, h = tid & 1;
    const long grow = (long)blockIdx.x * 128 + r;
    const float* ap = act + grow * 128 + h * 64;
    const float* ep = ema + grow * 128 + h * 64;
    float4 a4[16];
    float a2 = 0.f, e2 = 0.f, ae = 0.f;
#pragma unroll
    for (int j = 0; j < 16; ++j) {
      a4[j] = *(const float4*)(ap + 4 * j);
      const float4 ev = *(const float4*)(ep + 4 * j);
      a2 += a4[j].x*a4[j].x + a4[j].y*a4[j].y + a4[j].z*a4[j].z + a4[j].w*a4[j].w;
      e2 += ev.x*ev.x + ev.y*ev.y + ev.z*ev.z + ev.w*ev.w;
      ae += a4[j].x*ev.x + a4[j].y*ev.y + a4[j].z*ev.z + a4[j].w*ev.w;
    }
    a2 += __shfl_xor(a2, 1); e2 += __shfl_xor(e2, 1); ae += __shfl_xor(ae, 1);
    const float rna = rsqrtf(a2), rne = rsqrtf(e2);
    mylpos = ae * rna * rne * C2L;
    int mylab;
    {
      const float* pp = plab + grow * CLASS_NUM;
      float best = pp[0]; int bix = 0;
#pragma unroll
      for (int c = 1; c < CLASS_NUM; ++c) {
        const float vv = pp[c];
        if (vv > best) { best = vv; bix = c; }
      }
      mylab = bix;
    }
    {
      const float* qs = (const float*)(ws + QSUM_OFF) + mylab * 128 + h * 64;
      float pdot = 0.f;
#pragma unroll
      for (int j = 0; j < 16; ++j) {
        const float4 qv = *(const float4*)(qs + 4 * j);
        pdot += a4[j].x*qv.x + a4[j].y*qv.y + a4[j].z*qv.z + a4[j].w*qv.w;
      }
      pdot *= rna;
      mypd = pdot + __shfl_xor(pdot, 1);
    }
    const float sc = rna * C2L;
#pragma unroll
    for (int j = 0; j < 32; ++j) {
      const float e0 = ((const float*)&a4[j >> 1])[(j & 1) * 2];
      const float e1 = ((const float*)&a4[j >> 1])[(j & 1) * 2 + 1];
      *(unsigned*)(aT + swz(r, h * 128 + 4 * j)) = f2bf_pack(e0 * sc, e1 * sc);
    }
  }
  __syncthreads();
  bf16x8 af[2][4];
#pragma unroll
  for (int s = 0; s < 2; ++s)
#pragma unroll
    for (int k = 0; k < 4; ++k)
      af[s][k] = *(const bf16x8*)(aT + swz(wave * 32 + s * 16 + lo, k * 64 + hi * 16));
  float dn[2][4] = {{0.f,0.f,0.f,0.f},{0.f,0.f,0.f,0.f}};
  for (int t = 0; t < NQT; ++t) {
    const int cur = t & 1;
    if (t < NQT - 1) {
      const char* gs = ws + (size_t)(t + 1) * TBYTES + wave * 4096 + lane * 16;
      char* ld = qT[cur ^ 1] + wave * 4096;
#pragma unroll
      for (int ii = 0; ii < 4; ++ii)
        __builtin_amdgcn_global_load_lds(
            (const __attribute__((address_space(1))) void*)(gs + ii * 1024),
            (__attribute__((address_space(3))) void*)(ld + ii * 1024), 16, 0, 0);
    }
    const char* qb = qT[cur];
#pragma unroll
    for (int n = 0; n < 4; ++n) {
      bf16x8 bf[4];
#pragma unroll
      for (int k = 0; k < 4; ++k)
        bf[k] = *(const bf16x8*)(qb + swz(n * 16 + lo, k * 64 + hi * 16));
      f32x4 acc0 = {0.f,0.f,0.f,0.f}, acc1 = {0.f,0.f,0.f,0.f};
#pragma unroll
      for (int k = 0; k < 4; ++k)
        acc0 = __builtin_amdgcn_mfma_f32_16x16x32_bf16(af[0][k], bf[k], acc0, 0, 0, 0);
#pragma unroll
      for (int k = 0; k < 4; ++k)
        acc1 = __builtin_amdgcn_mfma_f32_16x16x32_bf16(af[1][k], bf[k], acc1, 0, 0, 0);
#pragma unroll
      for (int rg = 0; rg < 4; ++rg) {
        dn[0][rg] += exp2f(acc0[rg]);
        dn[1][rg] += exp2f(acc1[rg]);
      }
    }
    __syncthreads();
  }
#pragma unroll
  for (int s = 0; s < 2; ++s)
#pragma unroll
    for (int rg = 0; rg < 4; ++rg)
#pragma unroll
      for (int m = 1; m < 16; m <<= 1)
        dn[s][rg] += __shfl_xor(dn[s][rg], m);
  float loss = 0.f;
  if (lo == 0) {
#pragma unroll
    for (int s = 0; s < 2; ++s)
#pragma unroll
      for (int rg = 0; rg < 4; ++rg) {
        const int idx = (s * 16 + hi * 4 + rg) * 2;
        const float lp  = exp2f(__shfl(mylpos, idx));
        const float pdr = __shfl(mypd, idx);
        const float dnf = lp + dn[s][rg] - (float)NPAD;
        loss += -logf(lp / dnf + 1e-8f) + 150.0f * logf(dnf) - 2.0f * pdr;
      }
  }
#pragma unroll
  for (int m = 1; m < 64; m <<= 1) loss += __shfl_xor(loss, m);
  float* swsum = (float*)aT;
  if (lane == 0) swsum[wave] = loss;
  __syncthreads();
  if (tid == 0)
    atomicAdd(out, (swsum[0] + swsum[1] + swsum[2] + swsum[3]) *
                       (1.0f / (151.0f * 65536.0f)));
}

extern "C" void kernel_launch(void* const* d_in, const int* in_sizes, int n_in,
                              void* d_out, int out_size, void* d_ws, size_t ws_size,
                              hipStream_t stream) {
  const float* act   = (const float*)d_in[0];
  const float* ema   = (const float*)d_in[1];
  const float* plab  = (const float*)d_in[2];
  const float* queue = (const float*)d_in[3];
  float* out = (float*)d_out;

  hipMemsetAsync(d_out, 0, sizeof(float), stream);

  prep_queue<<<dim3((QPAD * 64 + 255) / 256), dim3(256), 0, stream>>>(
      queue, (unsigned*)d_ws);
  prep_qsum<<<dim3(CLASS_NUM), dim3(128), 0, stream>>>(
      queue, (float*)((char*)d_ws + QSUM_OFF));

  if (ws_size >= WS_NEED) {
    prep_act<<<dim3(2048), dim3(256), 0, stream>>>(act, ema, plab, (char*)d_ws);
    pgc_gemm<<<dim3(512), dim3(512), 0, stream>>>((const char*)d_ws, out);
  } else {
    pgc_main<<<dim3(512), dim3(256), 0, stream>>>(
        act, ema, plab, (const char*)d_ws, out);
  }
}